// Round 12
// baseline (110.567 us; speedup 1.0000x reference)
//
#include <hip/hip_runtime.h>
#include <math.h>

#define BB 32
#define TT 1024
#define HH 128

typedef __attribute__((ext_vector_type(8))) short short8;
typedef __attribute__((ext_vector_type(4))) float floatx4;

__device__ __forceinline__ unsigned short f2bf(float f) {
    unsigned u = __float_as_uint(f);
    u += 0x7fffu + ((u >> 16) & 1u);
    return (unsigned short)(u >> 16);
}

// Kernel A: gather embedding rows, normalize (store bf16), compute lambda.
__global__ __launch_bounds__(256)
void gather_norm(const int* __restrict__ seq,
                 const float* __restrict__ embd,
                 const float* __restrict__ lam_w,
                 const float* __restrict__ lam_b,
                 unsigned short* __restrict__ xbf,
                 float* __restrict__ lam) {
    const int lane = threadIdx.x & 63;
    const int half = lane >> 5;
    const int l32  = lane & 31;
    const int row  = blockIdx.x * 8 + (threadIdx.x >> 6) * 2 + half;
    const int idx  = seq[row];
    float4 v = ((const float4*)(embd + (size_t)idx * HH))[l32];
    float4 w = ((const float4*)lam_w)[l32];
    float ss = v.x * v.x + v.y * v.y + v.z * v.z + v.w * v.w;
    float dw = v.x * w.x + v.y * w.y + v.z * w.z + v.w * w.w;
    #pragma unroll
    for (int off = 16; off > 0; off >>= 1) {
        ss += __shfl_xor(ss, off);
        dw += __shfl_xor(dw, off);
    }
    float inv = 1.0f / sqrtf(ss);
    unsigned b0 = f2bf(v.x * inv), b1 = f2bf(v.y * inv);
    unsigned b2 = f2bf(v.z * inv), b3 = f2bf(v.w * inv);
    uint2 o; o.x = b0 | (b1 << 16); o.y = b2 | (b3 << 16);
    ((uint2*)(xbf + (size_t)row * HH))[l32] = o;
    if (l32 == 0) lam[row] = expf(dw + lam_b[0]);
}

// local partials for one (tile, t-group): no cross-lane ops.
__device__ __forceinline__ void tile_part(const floatx4& acc, int s0, int t,
                                          float lmt, const float4& yv,
                                          float& S, float& W, float& Y) {
    float v0 = (s0 + 0 < t) ? (acc[0] + 1.f) * 0.5f : 0.f;
    float v1 = (s0 + 1 < t) ? (acc[1] + 1.f) * 0.5f : 0.f;
    float v2 = (s0 + 2 < t) ? (acc[2] + 1.f) * 0.5f : 0.f;
    float v3 = (s0 + 3 < t) ? (acc[3] + 1.f) * 0.5f : 0.f;
    float suf3 = v3;
    float suf2 = v2 + suf3;
    float suf1 = v1 + suf2;
    float suf0 = v0 + suf1;
    float e0 = __expf(-lmt * suf0);
    float e1 = __expf(-lmt * suf1);
    float e2 = __expf(-lmt * suf2);
    float e3 = __expf(-lmt * suf3);
    float w0 = v0 * e0, w1 = v1 * e1, w2 = v2 * e2, w3 = v3 * e3;
    S = suf0;
    W = (w0 + w1) + (w2 + w3);
    Y = (w0 * yv.x + w1 * yv.y) + (w2 * yv.z + w3 * yv.w);
}

// cross-quad resolution: apply deferred decay, update running total.
__device__ __forceinline__ void resolve(float S, float W, float Y, float lmt,
                                        int tl, int quad,
                                        float& above, float& wl, float& yl) {
    float q0 = __shfl(S, tl);
    float q1 = __shfl(S, tl + 16);
    float q2 = __shfl(S, tl + 32);
    float q3 = __shfl(S, tl + 48);
    float tT = (q0 + q1) + (q2 + q3);
    float hq = (quad < 1 ? q1 : 0.f) + (quad < 2 ? q2 : 0.f) +
               (quad < 3 ? q3 : 0.f);
    float sc = __expf(-lmt * (above + hq));
    wl += W * sc;
    yl += Y * sc;
    above += tT;
}

// Kernel B: one block per (b, u = 32-t supertile, half of s-range).
// Each supertile's s-range (2u+2 s-tiles) is split across TWO blocks
// (half 1 = higher s), doubling grid occupancy vs R7 (2048 blocks = 8/CU).
// Inside a block: 4 waves split the half's tiles (wave 3 = highest s);
// t-pairing (one A-tile load feeds 8 MFMAs); sub-batch of 2 s-tiles with
// hoisted loads; in-block LDS merge. Block writes (W, Y, T) partials per t;
// kernel C combines the two halves with the associative rescale.
__global__ __launch_bounds__(256, 4)
void sim_half(const unsigned short* __restrict__ xbf,
              const float* __restrict__ lam,
              const float* __restrict__ y,
              float* __restrict__ Wp,
              float* __restrict__ Yp,
              float* __restrict__ Tp) {
    const int b    = blockIdx.x & 31;
    const int r    = blockIdx.x >> 5;            // 0..63
    const int u    = 31 - (r >> 1);              // largest supertiles first
    const int half = r & 1;                      // 1 = higher s
    const int tid  = threadIdx.x;
    const int w    = tid >> 6;
    const int lane = tid & 63;
    const int tl   = lane & 15;
    const int quad = lane >> 4;

    const size_t rowbase = (size_t)b * TT;
    const int t0 = u * 32 + tl;
    const int t1 = t0 + 16;
    const float lam0 = lam[rowbase + t0];
    const float lam1 = lam[rowbase + t1];
    const float* yb = y + rowbase;

    __shared__ float Wc[4][2][16], Yc[4][2][16], Tc[4][2][16];

    // preload both B-fragment sets (t-tile 2u and 2u+1)
    short8 bq0[4], bq1[4];
    const short8* q0r = (const short8*)(xbf + (rowbase + t0) * HH);
    const short8* q1r = (const short8*)(xbf + (rowbase + t1) * HH);
    #pragma unroll
    for (int kk = 0; kk < 4; kk++) {
        bq0[kk] = q0r[kk * 4 + quad];
        bq1[kk] = q1r[kk * 4 + quad];
    }

    // this block's tiles: [half*(u+1), (half+1)*(u+1)); wave takes a quarter
    const int ntile = u + 1;
    const int base_tile = half * ntile;
    const int qn = ntile >> 2, rem = ntile & 3;
    const int cnt   = qn + (w < rem ? 1 : 0);
    const int start = base_tile + w * qn + (w < rem ? w : rem);

    float wl0 = 0.f, yl0 = 0.f, run0 = 0.f;
    float wl1 = 0.f, yl1 = 0.f, run1 = 0.f;

    const int nsb = (cnt + 1) >> 1;
    for (int sb = nsb - 1; sb >= 0; --sb) {
        const int jA = start + 2 * sb;          // lower s-tile
        const bool vB = (2 * sb + 1) < cnt;     // higher s-tile valid?
        const int sbaseA = jA << 4;
        const int sbaseB = vB ? ((jA + 1) << 4) : sbaseA;

        // ---- hoist ALL loads for the sub-batch ----
        const short8* arA = (const short8*)(xbf + (rowbase + sbaseA + tl) * HH);
        const short8* arB = (const short8*)(xbf + (rowbase + sbaseB + tl) * HH);
        short8 afA[4], afB[4];
        #pragma unroll
        for (int kk = 0; kk < 4; kk++) {
            afA[kk] = arA[kk * 4 + quad];
            afB[kk] = arB[kk * 4 + quad];
        }
        float4 yvA = ((const float4*)(yb + sbaseA))[quad];
        float4 yvB = ((const float4*)(yb + sbaseB))[quad];

        // ---- 16 MFMAs, 4 independent acc chains ----
        floatx4 aA0 = {0,0,0,0}, aA1 = {0,0,0,0};
        floatx4 aB0 = {0,0,0,0}, aB1 = {0,0,0,0};
        #pragma unroll
        for (int kk = 0; kk < 4; kk++) {
            aA0 = __builtin_amdgcn_mfma_f32_16x16x32_bf16(afA[kk], bq0[kk], aA0, 0, 0, 0);
            aA1 = __builtin_amdgcn_mfma_f32_16x16x32_bf16(afA[kk], bq1[kk], aA1, 0, 0, 0);
            aB0 = __builtin_amdgcn_mfma_f32_16x16x32_bf16(afB[kk], bq0[kk], aB0, 0, 0, 0);
            aB1 = __builtin_amdgcn_mfma_f32_16x16x32_bf16(afB[kk], bq1[kk], aB1, 0, 0, 0);
        }

        const int s0A = sbaseA + quad * 4;
        const int s0B = vB ? (sbaseB + quad * 4) : 0x40000000;  // masks all

        // ---- local partials (no cross-lane) ----
        float SB0, WB0, YB0, SB1, WB1, YB1;
        float SA0, WA0, YA0, SA1, WA1, YA1;
        tile_part(aB0, s0B, t0, lam0, yvB, SB0, WB0, YB0);
        tile_part(aB1, s0B, t1, lam1, yvB, SB1, WB1, YB1);
        tile_part(aA0, s0A, t0, lam0, yvA, SA0, WA0, YA0);
        tile_part(aA1, s0A, t1, lam1, yvA, SA1, WA1, YA1);

        // ---- resolution: tile B (higher s) first, then tile A ----
        resolve(SB0, WB0, YB0, lam0, tl, quad, run0, wl0, yl0);
        resolve(SB1, WB1, YB1, lam1, tl, quad, run1, wl1, yl1);
        resolve(SA0, WA0, YA0, lam0, tl, quad, run0, wl0, yl0);
        resolve(SA1, WA1, YA1, lam1, tl, quad, run1, wl1, yl1);
    }

    // ---- cross-quad final reduce, wave partials to LDS ----
    float Wt0 = __shfl(wl0, tl) + __shfl(wl0, tl + 16) +
                __shfl(wl0, tl + 32) + __shfl(wl0, tl + 48);
    float Yt0 = __shfl(yl0, tl) + __shfl(yl0, tl + 16) +
                __shfl(yl0, tl + 32) + __shfl(yl0, tl + 48);
    float Wt1 = __shfl(wl1, tl) + __shfl(wl1, tl + 16) +
                __shfl(wl1, tl + 32) + __shfl(wl1, tl + 48);
    float Yt1 = __shfl(yl1, tl) + __shfl(yl1, tl + 16) +
                __shfl(yl1, tl + 32) + __shfl(yl1, tl + 48);
    if (quad == 0) {
        Wc[w][0][tl] = Wt0; Yc[w][0][tl] = Yt0; Tc[w][0][tl] = run0;
        Wc[w][1][tl] = Wt1; Yc[w][1][tl] = Yt1; Tc[w][1][tl] = run1;
    }
    __syncthreads();

    // ---- merge 4 wave-chunks; write block partials (W, Y, T) per t ----
    if (tid < 32) {
        const int g = tid >> 4, l = tid & 15;
        const int t = u * 32 + g * 16 + l;
        const float lt = lam[rowbase + t];
        float A = 0.f, W = 0.f, Y = 0.f;
        #pragma unroll
        for (int ww = 3; ww >= 0; --ww) {
            float sc = __expf(-lt * A);
            W += Wc[ww][g][l] * sc;
            Y += Yc[ww][g][l] * sc;
            A += Tc[ww][g][l];
        }
        const int p = (b * 64 + u * 2 + half) * 32 + tid;
        Wp[p] = W; Yp[p] = Y; Tp[p] = A;
    }
}

// Kernel C: combine the two half partials per (b, u, t).
__global__ __launch_bounds__(256)
void merge2(const float* __restrict__ Wp,
            const float* __restrict__ Yp,
            const float* __restrict__ Tp,
            const float* __restrict__ lam,
            float* __restrict__ out) {
    const int id   = blockIdx.x * 256 + threadIdx.x;   // 0..32767
    const int tcol = id & 31;
    const int u    = (id >> 5) & 31;
    const int b    = id >> 10;
    const int t    = u * 32 + tcol;
    const float lt = lam[b * TT + t];
    const int p0 = (b * 64 + u * 2) * 32 + tcol;       // lower-s half
    const int p1 = p0 + 32;                            // higher-s half
    float W = Wp[p1] + __expf(-lt * Tp[p1]) * Wp[p0];
    float Y = Yp[p1] + __expf(-lt * Tp[p1]) * Yp[p0];
    float r = Y / (W + 1e-6f);
    out[b * TT + t] = fminf(fmaxf(r, 0.01f), 0.99f);
}

extern "C" void kernel_launch(void* const* d_in, const int* in_sizes, int n_in,
                              void* d_out, int out_size, void* d_ws, size_t ws_size,
                              hipStream_t stream) {
    const float* y     = (const float*)d_in[0];
    const int*   seq   = (const int*)  d_in[1];
    const float* embd  = (const float*)d_in[2];
    const float* lam_w = (const float*)d_in[3];
    const float* lam_b = (const float*)d_in[4];
    float* out = (float*)d_out;

    unsigned short* xbf = (unsigned short*)d_ws;            // 8 MB
    float* lam = (float*)(xbf + (size_t)BB * TT * HH);      // 128 KB
    float* Wp  = lam + BB * TT;                             // 256 KB
    float* Yp  = Wp + BB * 64 * 32;                         // 256 KB
    float* Tp  = Yp + BB * 64 * 32;                         // 256 KB

    gather_norm<<<BB * TT / 8, 256, 0, stream>>>(seq, embd, lam_w, lam_b, xbf, lam);
    sim_half<<<BB * 64, 256, 0, stream>>>(xbf, lam, y, Wp, Yp, Tp);
    merge2<<<BB * TT / 256, 256, 0, stream>>>(Wp, Yp, Tp, lam, out);
}